// Round 20
// baseline (2176.795 us; speedup 1.0000x reference)
//
#include <hip/hip_runtime.h>
#include <hip/hip_bf16.h>
#include <math.h>

#define BTOT   16384
#define NLAYER 24
#define NDIN   12
#define HID    192
#define NBASE  66
#define EPSP   1e-3f
#define EPB    8         // elements per block; 128 threads; grid 2048

// ------------- LDS layout (bytes), 38,432 total, dynamic --------------
// R31 = R29/R30 resubmitted (two container infra failures; kernel never
// ran — audited memory-safe, R28 near-identical source ran fine).
// R29 = R28 with the z-state guard bug fixed: EPB=8 -> z-state set is
// 6 dims x 8 elems = 48 threads (R28 kept tid<96 from EPB=16 -> OOB yz
// reads + sZ1 overflow into sLD/sZQ -> absmax 30). Three sites fixed:
// init, phase C, final writeback (tid<48, i=tid>>3 in 0..5).
// Structure: 4 barrier domains x 2 waves (was 2x4). Same 8 waves/CU,
// same 5 barriers/layer; each s_barrier parks 2 waves while 6 waves in
// 3 other blocks keep issuing (R11 1dom=1680 vs R16 3dom=1520 evidence).
#define EST 200          // j/k stride (shorts); 400-B rows, 16B-aligned
#define W3ST 12          // sW3f row stride in floats (== row length; never shrink)
#define OB_H1  0         // ushort[8*200]    3200 : h1 bf16 [e][k]
#define OB_G   3200      // ushort[48*200]  19200 : h2 rows 0-7, then G full [(r,e)][j]
#define OB_R   22400     // float[72*8]      2304 : cotangent rows [rt][e]
#define OB_W1  24704     // ushort[192*6]    2304 : W1 bf16, 12-B rows
#define OB_W3F 27008     // float[192*12]    9216 : W3 fp32 [j][t]
#define OB_PRM 36224     // float[2][12*8]    768 : prm sums / tf,es (layer-parity dbuf)
#define OB_GZ  36992     // float[6*48]      1152 : g_z1 sums [i][g=r*8+e] (atomics)
#define OB_Z1  38144     // float[6*8]        192 : z[6..12) for next F1
#define OB_LD  38336     // float[8]           32 : logdet acc
#define OB_ZQ  38368     // float[8]           32 : sum z^2
#define OB_RED 38400     // float[8]           32
#define SMEM_BYTES 38432

typedef __attribute__((ext_vector_type(8))) short s8v;
typedef __attribute__((ext_vector_type(4))) float f4v;
#define MFMA16(a,b,c) __builtin_amdgcn_mfma_f32_16x16x32_bf16(a,b,c,0,0,0)

__device__ __forceinline__ unsigned short f2bf(float f) {
  unsigned u = __builtin_bit_cast(unsigned, f);
  u += 0x7fffu + ((u >> 16) & 1u);          // RNE
  return (unsigned short)(u >> 16);
}
__device__ __forceinline__ float bf2f(unsigned short h) {
  unsigned u = ((unsigned)h) << 16;
  return __builtin_bit_cast(float, u);
}
__device__ __forceinline__ unsigned pk2(float a, float b) {
  return (unsigned)f2bf(a) | ((unsigned)f2bf(b) << 16);
}
__device__ __forceinline__ float blo(unsigned u) { return bf2f((unsigned short)(u & 0xffff)); }
__device__ __forceinline__ float bhi(unsigned u) { return bf2f((unsigned short)(u >> 16)); }

// ---------------------------------------------------------------------
__global__ void prep_kernel(const float* __restrict__ W2,
                            unsigned short* __restrict__ w2b,
                            unsigned short* __restrict__ w2t) {
  int idx = blockIdx.x * 256 + threadIdx.x;   // 884736 exact
  int l   = idx / (HID * HID);
  int rem = idx - l * HID * HID;
  int k   = rem / HID;
  int j   = rem - k * HID;
  w2b[idx] = f2bf(W2[idx]);                         // [l][j][k]
  w2t[idx] = f2bf(W2[l * HID * HID + j * HID + k]); // [l][k][j]
}

// ---------------------------------------------------------------------
// flow_kernel: block = 8 elements, 128 threads = 2 waves, 4 blocks/CU.
// 5 barriers/layer: A | B | C | D | E. B: wave w -> 6 m-tiles (w+2s),
// half-density B operand (cols lm>=8 garbage, guarded). E: wave w ->
// 6m x 3n in 2 sub-passes of 3m x 3n (acc 36), G = 48 rows.
__global__ __launch_bounds__(128) void flow_kernel(
    float* __restrict__ yz, float* __restrict__ jp,
    const float* __restrict__ W1, const float* __restrict__ b1,
    const float* __restrict__ b2,
    const float* __restrict__ W3, const float* __restrict__ b3,
    const unsigned short* __restrict__ w2b,
    const unsigned short* __restrict__ w2t,
    float* __restrict__ ws_sum, float* __restrict__ out_lp) {
  extern __shared__ char smraw[];
  unsigned short* sH1b = (unsigned short*)(smraw + OB_H1);
  unsigned short* sGb  = (unsigned short*)(smraw + OB_G);
  float* sW3f = (float*)(smraw + OB_W3F);
  float* sR   = (float*)(smraw + OB_R);
  float* sPRM = (float*)(smraw + OB_PRM);   // 2 x 96 floats
  float* sGZ  = (float*)(smraw + OB_GZ);
  float* sZ1  = (float*)(smraw + OB_Z1);
  float* sLD  = (float*)(smraw + OB_LD);
  float* sZQ  = (float*)(smraw + OB_ZQ);
  float* sRed = (float*)(smraw + OB_RED);

  const int tid  = threadIdx.x;
  const int lane = tid & 63;
  const int w    = __builtin_amdgcn_readfirstlane(tid >> 6);  // 0..1
  const int e    = tid & 7;                      // element (scalar phases)
  const int grp  = tid >> 3;                     // 0..15
  const int lm   = lane & 15, lq = lane >> 4;    // MFMA lane coords
  const int em   = lm & 7;                       // element index of lane
  const int blk  = blockIdx.x;

  // ---- init: z-state held by tid<48 (i = tid>>3 in 0..5) ----
  float z_a = 0.f, z_b = 0.f;
  if (tid < 48) {
    int i = tid >> 3;
    z_a = yz[(blk * EPB + e) * 12 + i];
    z_b = yz[(blk * EPB + e) * 12 + 6 + i];
    sZ1[i * EPB + e] = z_b;
  }
  if (tid < 8) { sLD[tid] = 0.f; sZQ[tid] = 0.f; }
  if (tid == 0) sRed[0] = 0.f;
  for (int idx = tid; idx < 288; idx += 128) sGZ[idx] = 0.f;
  for (int idx = tid; idx < 192; idx += 128) sPRM[idx] = 0.f;
  for (int idx = tid; idx < 72 * EPB; idx += 128) {
    int rt = idx >> 3, ee = idx & 7;
    sR[idx] = jp[(blk * EPB + ee) * 72 + rt];
  }
  __syncthreads();

  for (int l = NLAYER - 1; l >= 0; --l) {
    const float* W1l = W1 + l * HID * 6;
    const float* b1l = b1 + l * HID;
    const float* b2l = b2 + l * HID;
    const float* W3l = W3 + l * NDIN * HID;
    const float* b3l = b3 + l * NDIN;
    const unsigned short* w2bl = w2b + l * HID * HID;
    const unsigned short* w2tl = w2t + l * HID * HID;
    float* cur = sPRM + (l & 1) * 96;           // this layer's prm/tf/es
    float* prv = sPRM + ((l + 1) & 1) * 96;     // previous layer's tf/es

    // ==== Phase A (merged): stage W1+W3f, zero cur, V5(l+1), F1(l) ======
    for (int j = tid; j < 192; j += 128) {
      const float* wr = W1l + j * 6;
      unsigned* dst = (unsigned*)(smraw + OB_W1 + j * 12);
      dst[0] = pk2(wr[0], wr[1]);
      dst[1] = pk2(wr[2], wr[3]);
      dst[2] = pk2(wr[4], wr[5]);
    }
    for (int idx = tid; idx < 2304; idx += 128) {   // W3f [j][t], stride 12
      int t = idx / 192, j = idx - t * 192;
      sW3f[j * W3ST + t] = W3l[idx];
    }
    if (tid < 96) cur[tid] = 0.f;                   // 12*EPB = 96 floats
    if (l != NLAYER - 1) {                          // V5 of layer l+1
      for (int idx = tid; idx < 288; idx += 128) {
        int i = idx / 48, rem = idx - i * 48;
        int r = rem >> 3, e5 = rem & 7;
        float r1  = sR[(r * 12 + i) * EPB + e5];
        float r2o = sR[(r * 12 + 6 + i) * EPB + e5];
        float es  = prv[(2 * i + 1) * EPB + e5];
        sR[(r * 12 + i) * EPB + e5]     = r2o + sGZ[i * 48 + rem];
        sR[(r * 12 + 6 + i) * EPB + e5] = r1 * es;
        sGZ[i * 48 + rem] = 0.f;
      }
    }
    {                                               // F1: 12 rows per grp
      float z1v[6];
      #pragma unroll
      for (int i = 0; i < 6; ++i) z1v[i] = sZ1[i * EPB + e];
      #pragma unroll
      for (int ch = 0; ch < 2; ++ch) {
        int j0 = grp * 12 + ch * 6;
        float hv[6];
        #pragma unroll
        for (int jj = 0; jj < 6; ++jj) {
          int j = j0 + jj;
          float acc = b1l[j];
          #pragma unroll
          for (int i = 0; i < 6; ++i) acc = fmaf(W1l[j * 6 + i], z1v[i], acc);
          hv[jj] = fmaxf(acc, 0.f);
        }
        unsigned* dst = (unsigned*)&sH1b[e * EST + j0];
        dst[0] = pk2(hv[0], hv[1]);
        dst[1] = pk2(hv[2], hv[3]);
        dst[2] = pk2(hv[4], hv[5]);
      }
    }
    __syncthreads();

    // ==== Phase B: F2 MFMA; wave w: 6 m-tiles (w+2s), half-density B ===
    // B-operand rows lm>=8 read garbage (beyond 8-row h1, within LDS
    // allocation) -> outputs for columns lm>=8 are garbage and are
    // discarded (guards below). MFMA columns are independent.
    {
      f4v acc2[6] = {{0,0,0,0},{0,0,0,0},{0,0,0,0},
                     {0,0,0,0},{0,0,0,0},{0,0,0,0}};
      #pragma unroll 2
      for (int kk = 0; kk < 6; ++kk) {
        int jo = kk * 32 + lq * 8;
        s8v Bv = *(const s8v*)&sH1b[lm * EST + jo];   // lm>=8: garbage, safe
        #pragma unroll
        for (int s = 0; s < 6; ++s) {
          s8v A = *(const s8v*)(w2bl + ((w + s * 2) * 16 + lm) * HID + jo);
          acc2[s] = MFMA16(A, Bv, acc2[s]);
        }
      }
      #pragma unroll
      for (int s = 0; s < 6; ++s) {
        int jb2 = (w + s * 2) * 16 + lq * 4;
        float hv[4];
        #pragma unroll
        for (int rg = 0; rg < 4; ++rg)
          hv[rg] = fmaxf(acc2[s][rg] + b2l[jb2 + rg], 0.f);
        if (lm < 8) {                               // h2 store: valid rows only
          unsigned* dst = (unsigned*)sGb + ((lm * EST + jb2) >> 1);
          dst[0] = pk2(hv[0], hv[1]);
          dst[1] = pk2(hv[2], hv[3]);
        }
        float pp[12];
        #pragma unroll
        for (int t = 0; t < 12; ++t) pp[t] = 0.f;
        #pragma unroll
        for (int rg = 0; rg < 4; ++rg) {
          const float* w3r = sW3f + (jb2 + rg) * W3ST;
          float v = hv[rg];
          #pragma unroll
          for (int t = 0; t < 12; ++t) pp[t] = fmaf(w3r[t], v, pp[t]);
        }
        #pragma unroll
        for (int t = 0; t < 12; ++t) {
          float v = pp[t];
          v += __shfl_xor(v, 16);
          v += __shfl_xor(v, 32);
          if (lane < 8) atomicAdd(&cur[t * EPB + lane], v);
        }
      }
    }
    __syncthreads();

    // ==== Phase C: U — coupling update (tid<48, i in 0..5) =============
    if (tid < 48) {
      int i = tid >> 3;
      float sh = b3l[2 * i]     + cur[(2 * i) * EPB + e];
      float sr = b3l[2 * i + 1] + cur[(2 * i + 1) * EPB + e];
      float s  = 2.f * tanhf(0.5f * sr);
      float es = expf(s), en = expf(-s);
      float tv = z_a - sh;
      z_a = z_b;
      z_b = tv * en;
      sZ1[i * EPB + e] = z_b;
      cur[(2 * i) * EPB + e]     = tv * (1.f - 0.25f * s * s);  // tf
      cur[(2 * i + 1) * EPB + e] = es;                          // es
      atomicAdd(&sLD[e], -s);
    }
    __syncthreads();

    // ==== Phase D: full-G build — all 6 cotangent rows, one pass =======
    // G row g = r*8+e (48 rows). Thread (grp,e) reads its own h2 row e
    // cols [12grp,12grp+12) (mbits) and is the sole writer of G row e
    // (r=0) at those cols -> no race.
    {
      unsigned mbits = 0;
      {
        const unsigned* hp = (const unsigned*)&sGb[e * EST + grp * 12];
        #pragma unroll
        for (int c = 0; c < 6; ++c) {
          unsigned m = hp[c];
          mbits |= ((m & 0xffffu) ? 1u : 0u) << (2 * c);
          mbits |= ((m >> 16)     ? 1u : 0u) << (2 * c + 1);
        }
      }
      float tf[6];
      #pragma unroll
      for (int c = 0; c < 6; ++c) tf[c] = cur[(2 * c) * EPB + e];
      float r1[6][6];
      #pragma unroll
      for (int r = 0; r < 6; ++r)
        #pragma unroll
        for (int c = 0; c < 6; ++c)
          r1[r][c] = sR[(r * 12 + c) * EPB + e];
      #pragma unroll
      for (int ch = 0; ch < 2; ++ch) {
        int j0 = grp * 12 + ch * 6;
        #pragma unroll
        for (int pr = 0; pr < 3; ++pr) {
          const float* wp0 = sW3f + (j0 + 2 * pr)     * W3ST;
          const float* wp1 = sW3f + (j0 + 2 * pr + 1) * W3ST;
          float wc0[6], wc1[6];
          #pragma unroll
          for (int c = 0; c < 6; ++c) {
            wc0[c] = fmaf(tf[c], wp0[2 * c + 1], wp0[2 * c]);
            wc1[c] = fmaf(tf[c], wp1[2 * c + 1], wp1[2 * c]);
          }
          unsigned b0 = (mbits >> (ch * 6 + 2 * pr))     & 1u;
          unsigned b1 = (mbits >> (ch * 6 + 2 * pr + 1)) & 1u;
          #pragma unroll
          for (int r = 0; r < 6; ++r) {
            float a0 = 0.f, a1 = 0.f;
            #pragma unroll
            for (int c = 0; c < 6; ++c) {
              a0 = fmaf(wc0[c], r1[r][c], a0);
              a1 = fmaf(wc1[c], r1[r][c], a1);
            }
            *(unsigned*)&sGb[(r * 8 + e) * EST + j0 + 2 * pr] =
                pk2(b0 ? a0 : 0.f, b1 ? a1 : 0.f);
          }
        }
      }
    }
    __syncthreads();

    // ==== Phase E: V3 48-row G; wave w: 6m x 3n in 2 sub-passes ========
    // n-tile q covers G rows [16q,16q+16): row = 16q+lm -> element =
    // lm&7 = em, r = 2q+(lm>>3). h1 mask = sH1b[em] (uniform over q).
    {
      #pragma unroll 1
      for (int mh = 0; mh < 2; ++mh) {
        const int mtg = w * 6 + mh * 3;             // 3 m-tiles this pass
        f4v acc[3][3] = {{{0,0,0,0},{0,0,0,0},{0,0,0,0}},
                         {{0,0,0,0},{0,0,0,0},{0,0,0,0}},
                         {{0,0,0,0},{0,0,0,0},{0,0,0,0}}};
        #pragma unroll 2
        for (int kk = 0; kk < 6; ++kk) {
          int jo = kk * 32 + lq * 8;
          s8v A[3], Bv[3];
          #pragma unroll
          for (int p = 0; p < 3; ++p)
            A[p] = *(const s8v*)(w2tl + ((mtg + p) * 16 + lm) * HID + jo);
          #pragma unroll
          for (int q = 0; q < 3; ++q)
            Bv[q] = *(const s8v*)&sGb[(q * 16 + lm) * EST + jo];
          #pragma unroll
          for (int p = 0; p < 3; ++p)
            #pragma unroll
            for (int q = 0; q < 3; ++q)
              acc[p][q] = MFMA16(A[p], Bv[q], acc[p][q]);
        }
        float pz[3][6];
        #pragma unroll
        for (int q = 0; q < 3; ++q)
          #pragma unroll
          for (int i = 0; i < 6; ++i) pz[q][i] = 0.f;
        #pragma unroll
        for (int p = 0; p < 3; ++p) {
          int kb = (mtg + p) * 16 + lq * 4;
          const unsigned* mp = (const unsigned*)&sH1b[em * EST + kb];
          unsigned mm0 = mp[0], mm1 = mp[1];
          #pragma unroll
          for (int rg = 0; rg < 4; ++rg) {   // stream w1v per-rg (12-B rows)
            const unsigned* wp =
                (const unsigned*)(smraw + OB_W1 + (kb + rg) * 12);
            unsigned wx = wp[0], wy = wp[1], wz = wp[2];
            float w0 = blo(wx), w1c = bhi(wx), w2c = blo(wy);
            float w3c = bhi(wy), w4c = blo(wz), w5c = bhi(wz);
            unsigned mm = (rg >> 1) ? mm1 : mm0;
            unsigned short hb = (rg & 1) ? (unsigned short)(mm >> 16)
                                         : (unsigned short)(mm & 0xffffu);
            #pragma unroll
            for (int q = 0; q < 3; ++q) {
              float val = hb ? acc[p][q][rg] : 0.f;
              pz[q][0] = fmaf(w0, val, pz[q][0]);
              pz[q][1] = fmaf(w1c, val, pz[q][1]);
              pz[q][2] = fmaf(w2c, val, pz[q][2]);
              pz[q][3] = fmaf(w3c, val, pz[q][3]);
              pz[q][4] = fmaf(w4c, val, pz[q][4]);
              pz[q][5] = fmaf(w5c, val, pz[q][5]);
            }
          }
        }
        #pragma unroll
        for (int q = 0; q < 3; ++q)
          #pragma unroll
          for (int i = 0; i < 6; ++i) {
            float v = pz[q][i];
            v += __shfl_xor(v, 16);
            v += __shfl_xor(v, 32);
            if (lane < 16)
              atomicAdd(&sGZ[i * 48 + q * 16 + lane], v);
          }
      }
    }
    __syncthreads();
  }

  // ---- final V5 (layer 0, parity 0) + z/lp; then jp writeback ----
  {
    float* prv0 = sPRM;                             // (0 & 1) == 0
    for (int idx = tid; idx < 288; idx += 128) {
      int i = idx / 48, rem = idx - i * 48;
      int r = rem >> 3, e5 = rem & 7;
      float r1  = sR[(r * 12 + i) * EPB + e5];
      float r2o = sR[(r * 12 + 6 + i) * EPB + e5];
      float es  = prv0[(2 * i + 1) * EPB + e5];
      sR[(r * 12 + i) * EPB + e5]     = r2o + sGZ[i * 48 + rem];
      sR[(r * 12 + 6 + i) * EPB + e5] = r1 * es;
    }
  }
  if (tid < 48) {
    int i = tid >> 3;
    yz[(blk * EPB + e) * 12 + i]     = z_a;
    yz[(blk * EPB + e) * 12 + 6 + i] = z_b;
    atomicAdd(&sZQ[e], fmaf(z_a, z_a, z_b * z_b));
  }
  __syncthreads();
  if (tid < 8)
    out_lp[blk * EPB + tid] = sLD[tid] - 11.027262398456072f - 0.5f * sZQ[tid];

  float part = 0.f;
  for (int idx = tid; idx < 72 * EPB; idx += 128) {
    int rt = idx >> 3, ee = idx & 7;
    float v = sR[idx];
    jp[(blk * EPB + ee) * 72 + rt] = v;
    part = fmaf(v, v, part);
  }
  #pragma unroll
  for (int off = 32; off > 0; off >>= 1) part += __shfl_down(part, off, 64);
  if ((tid & 63) == 0) atomicAdd(&sRed[0], part);
  __syncthreads();
  if (tid == 0) atomicAdd(ws_sum, sRed[0]);
}

// ---------------------------------------------------------------------
// kl_kernel R24 (verified): 4 slices/element, grid 256x256, A staged in
// LDS; partials shfl-reduced in the 4-lane group; slice 0 stores.
__global__ __launch_bounds__(256) void kl_kernel(
    const float* __restrict__ zin, const float* __restrict__ jpin,
    const float* __restrict__ Wsym, const float* __restrict__ lvd,
    const float* __restrict__ ws_sum, float* __restrict__ out_kl) {
  __shared__ float sA[NBASE * 144];        // 38,016 B
  const int tid   = threadIdx.x;
  const int elem  = (blockIdx.x * 256 + tid) >> 2;
  const int slice = tid & 3;

  for (int idx = tid; idx < NBASE * 144; idx += 256) {
    int m = idx / 144, r = idx - m * 144;
    int j = r / 12, i = r - j * 12;
    sA[idx] = Wsym[m * 144 + j * 12 + i] - Wsym[m * 144 + i * 12 + j];
  }
  __syncthreads();

  float z[12];
  #pragma unroll
  for (int i = 0; i < 12; ++i) z[i] = zin[elem * 12 + i];
  float scale = 1.0f / sqrtf(ws_sum[0]);
  float Jp[6][12];
  #pragma unroll
  for (int n = 0; n < 6; ++n)
    #pragma unroll
    for (int j = 0; j < 12; ++j)
      Jp[n][j] = jpin[elem * 72 + n * 12 + j] * scale;

  float Sq[78];
  #pragma unroll
  for (int i = 0; i < 78; ++i) Sq[i] = 0.f;
  float tq = 0.f, tpq = 0.f;

  const int m0 = (slice < 2) ? slice * 17 : 34 + (slice - 2) * 16;
  const int m1 = m0 + ((slice < 2) ? 17 : 16);
  for (int m = m0; m < m1; ++m) {
    const float* Am = sA + m * 144;
    float jq[12];
    #pragma unroll
    for (int j = 0; j < 12; ++j) {
      float acc = 0.f;
      #pragma unroll
      for (int i = 0; i < 12; ++i)
        acc = fmaf(Am[j * 12 + i], z[i], acc);
      jq[j] = acc;
    }
    #pragma unroll
    for (int i = 0; i < 12; ++i) {
      tq = fmaf(jq[i], jq[i], tq);
      #pragma unroll
      for (int j = 0; j <= i; ++j)
        Sq[i * (i + 1) / 2 + j] = fmaf(jq[i], jq[j], Sq[i * (i + 1) / 2 + j]);
    }
    #pragma unroll
    for (int n = 0; n < 6; ++n) {
      float d = 0.f;
      #pragma unroll
      for (int j = 0; j < 12; ++j) d = fmaf(Jp[n][j], jq[j], d);
      tpq = fmaf(d, d, tpq);
    }
  }

  #pragma unroll
  for (int i = 0; i < 78; ++i) {
    float v = Sq[i];
    v += __shfl_xor(v, 1);
    v += __shfl_xor(v, 2);
    Sq[i] = v;
  }
  tq  += __shfl_xor(tq, 1);  tq  += __shfl_xor(tq, 2);
  tpq += __shfl_xor(tpq, 1); tpq += __shfl_xor(tpq, 2);

  float Dv[12], Db[12];
  #pragma unroll
  for (int j = 0; j < 12; ++j) Dv[j] = expf(-lvd[j]);

  float mh = 0.f;
  #pragma unroll
  for (int i = 0; i < 12; ++i) mh += Sq[i * (i + 1) / 2 + i] + Dv[i];
  float norm_H = fmaxf(mh * (1.f / 12.f), 1e-6f);
  #pragma unroll
  for (int i = 0; i < 12; ++i) Sq[i * (i + 1) / 2 + i] += Dv[i] + 1e-3f * norm_H;
  float sumDb = 0.f;
  #pragma unroll
  for (int j = 0; j < 12; ++j) { Db[j] = Dv[j] + 1e-3f * norm_H; sumDb += Db[j]; }

  float M[21];
  #pragma unroll
  for (int n = 0; n < 6; ++n)
    #pragma unroll
    for (int mm = 0; mm <= n; ++mm) {
      float acc = 0.f;
      #pragma unroll
      for (int j = 0; j < 12; ++j) acc = fmaf(Jp[n][j], Jp[mm][j], acc);
      M[n * (n + 1) / 2 + mm] = acc;
    }
  float md = 0.f;
  #pragma unroll
  for (int i = 0; i < 6; ++i) md += M[i * (i + 1) / 2 + i];
  float norm_M = fmaxf(md * (1.f / 6.f) + EPSP, 1e-6f);
  #pragma unroll
  for (int i = 0; i < 6; ++i) M[i * (i + 1) / 2 + i] += EPSP + 1e-3f * norm_M;

  float trace_p = 0.f;
  #pragma unroll
  for (int n = 0; n < 6; ++n)
    #pragma unroll
    for (int j = 0; j < 12; ++j)
      trace_p = fmaf(Jp[n][j] * Jp[n][j], Db[j], trace_p);

  float trace = (EPSP + 1e-3f * norm_M) * (sumDb + tq) + trace_p + tpq;

  float ldM = 0.f;
  #pragma unroll
  for (int jc = 0; jc < 6; ++jc) {
    float d = M[jc * (jc + 1) / 2 + jc];
    #pragma unroll
    for (int k = 0; k < jc; ++k) d -= M[jc * (jc + 1) / 2 + k] * M[jc * (jc + 1) / 2 + k];
    d = sqrtf(d);
    ldM += logf(d);
    float di = 1.f / d;
    M[jc * (jc + 1) / 2 + jc] = d;
    #pragma unroll
    for (int i2 = jc + 1; i2 < 6; ++i2) {
      float v = M[i2 * (i2 + 1) / 2 + jc];
      #pragma unroll
      for (int k = 0; k < jc; ++k) v -= M[i2 * (i2 + 1) / 2 + k] * M[jc * (jc + 1) / 2 + k];
      M[i2 * (i2 + 1) / 2 + jc] = v * di;
    }
  }

  float ldH = 0.f;
  #pragma unroll
  for (int jc = 0; jc < 12; ++jc) {
    float d = Sq[jc * (jc + 1) / 2 + jc];
    #pragma unroll
    for (int k = 0; k < jc; ++k) d -= Sq[jc * (jc + 1) / 2 + k] * Sq[jc * (jc + 1) / 2 + k];
    d = sqrtf(d);
    ldH += logf(d);
    float di = 1.f / d;
    Sq[jc * (jc + 1) / 2 + jc] = d;
    #pragma unroll
    for (int i2 = jc + 1; i2 < 12; ++i2) {
      float v = Sq[i2 * (i2 + 1) / 2 + jc];
      #pragma unroll
      for (int k = 0; k < jc; ++k) v -= Sq[i2 * (i2 + 1) / 2 + k] * Sq[jc * (jc + 1) / 2 + k];
      Sq[i2 * (i2 + 1) / 2 + jc] = v * di;
    }
  }

  float logdet_p = 2.f * ldM + 6.f * logf(EPSP);
  float logdet_q = 2.f * ldH;
  if (slice == 0)
    out_kl[elem] = 0.5f * (trace - (logdet_p + logdet_q) - 12.f);
}

// ---------------------------------------------------------------------
extern "C" void kernel_launch(void* const* d_in, const int* in_sizes, int n_in,
                              void* d_out, int out_size, void* d_ws, size_t ws_size,
                              hipStream_t stream) {
  (void)in_sizes; (void)n_in; (void)out_size; (void)ws_size;
  float* y    = (float*)d_in[0];   // consumed, then overwritten with z
  float* Jp   = (float*)d_in[1];   // consumed, then overwritten with pullback Jp
  const float* W1   = (const float*)d_in[2];
  const float* b1   = (const float*)d_in[3];
  const float* W2   = (const float*)d_in[4];
  const float* b2   = (const float*)d_in[5];
  const float* W3   = (const float*)d_in[6];
  const float* b3   = (const float*)d_in[7];
  const float* Wsym = (const float*)d_in[8];
  const float* lvd  = (const float*)d_in[9];
  float* out = (float*)d_out;      // fp32: [log_prob (B), kl (B)]

  float* ws_sum = (float*)d_ws;
  unsigned short* w2b = (unsigned short*)((char*)d_ws + 256);
  unsigned short* w2t = (unsigned short*)((char*)d_ws + 256 +
                                          NLAYER * HID * HID * 2);
  hipMemsetAsync(d_ws, 0, 4, stream);

  hipFuncSetAttribute((const void*)flow_kernel,
                      hipFuncAttributeMaxDynamicSharedMemorySize, SMEM_BYTES);

  prep_kernel<<<3456, 256, 0, stream>>>(W2, w2b, w2t);
  flow_kernel<<<BTOT / EPB, 128, SMEM_BYTES, stream>>>(
      y, Jp, W1, b1, b2, W3, b3, w2b, w2t, ws_sum, out);
  kl_kernel<<<BTOT * 4 / 256, 256, 0, stream>>>(y, Jp, Wsym, lvd, ws_sum,
                                                out + BTOT);
}

// Round 21
// 1475.835 us; speedup vs baseline: 1.4750x; 1.4750x over previous
//
#include <hip/hip_runtime.h>
#include <hip/hip_bf16.h>
#include <math.h>

#define BTOT   16384
#define NLAYER 24
#define NDIN   12
#define HID    192
#define NBASE  66
#define EPSP   1e-3f
#define EPB    16        // elements per block; 256 threads; grid 1024

// ------------- LDS layout (bytes), 65,312 total, dynamic --------------
// R32 = FINAL: restore R27, the verified best (1480.9us total). R22's
// flow (5 barriers A|B|C|D|E, VGPR 120, 2 blocks/CU) + R24's kl
// (4-slice + LDS-staged A). Campaign ledger: occupancy class capped at
// 2 blocks/CU (R12-R21); 5 barriers minimal (R22/R23); cross-barrier
// prefetch impossible under the 128-VGPR wave-slot line (R25/R26);
// kl tail fixed (R24); 4x2-wave domain split falsified (R31: 2217us,
// half-density MFMA + doubled bank conflicts + residency loss).
#define EST 200          // j/k stride (shorts); 400-B rows, 16B-aligned
#define W3ST 12          // sW3f row stride in floats (== row length; never shrink)
#define OB_H1  0         // ushort[16*200]   6400 : h1 bf16 [e][k]
#define OB_G   6400      // ushort[96*200]  38400 : h2 rows 0-15, then G full [(r,e)][j]
#define OB_R   44800     // float[72*16]     4608 : cotangent rows [rt][e]
#define OB_W1  49408     // ushort[192*6]    2304 : W1 bf16, 12-B rows
#define OB_W3F 51712     // float[192*12]    9216 : W3 fp32 [j][t]
#define OB_PRM 60928     // float[2][12*16]  1536 : prm sums / tf,es (layer-parity dbuf)
#define OB_GZ  62464     // float[6*96]      2304 : g_z1 sums [i][r*16+e] (atomics)
#define OB_Z1  64768     // float[6*16]       384 : z[6..12) for next F1
#define OB_LD  65152     // float[16]          64 : logdet acc
#define OB_ZQ  65216     // float[16]          64 : sum z^2
#define OB_RED 65280     // float[8]           32
#define SMEM_BYTES 65312

typedef __attribute__((ext_vector_type(8))) short s8v;
typedef __attribute__((ext_vector_type(4))) float f4v;
#define MFMA16(a,b,c) __builtin_amdgcn_mfma_f32_16x16x32_bf16(a,b,c,0,0,0)

__device__ __forceinline__ unsigned short f2bf(float f) {
  unsigned u = __builtin_bit_cast(unsigned, f);
  u += 0x7fffu + ((u >> 16) & 1u);          // RNE
  return (unsigned short)(u >> 16);
}
__device__ __forceinline__ float bf2f(unsigned short h) {
  unsigned u = ((unsigned)h) << 16;
  return __builtin_bit_cast(float, u);
}
__device__ __forceinline__ unsigned pk2(float a, float b) {
  return (unsigned)f2bf(a) | ((unsigned)f2bf(b) << 16);
}
__device__ __forceinline__ float blo(unsigned u) { return bf2f((unsigned short)(u & 0xffff)); }
__device__ __forceinline__ float bhi(unsigned u) { return bf2f((unsigned short)(u >> 16)); }

// ---------------------------------------------------------------------
__global__ void prep_kernel(const float* __restrict__ W2,
                            unsigned short* __restrict__ w2b,
                            unsigned short* __restrict__ w2t) {
  int idx = blockIdx.x * 256 + threadIdx.x;   // 884736 exact
  int l   = idx / (HID * HID);
  int rem = idx - l * HID * HID;
  int k   = rem / HID;
  int j   = rem - k * HID;
  w2b[idx] = f2bf(W2[idx]);                         // [l][j][k]
  w2t[idx] = f2bf(W2[l * HID * HID + j * HID + k]); // [l][k][j]
}

// ---------------------------------------------------------------------
// flow_kernel: block = 16 elements, 256 threads = 4 waves, 2 blocks/CU.
// 5 barriers/layer: A | B | C | D | E (R22 structure, verified fastest).
// F2: wave w -> 3 m-tiles (w,w+4,w+8), acc2 = 12 AGPR. V3 (E): full
// 96-row G, wave w -> 3 m-tiles x 6 n-tiles in two barrier-free chunks.
__global__ __launch_bounds__(256) void flow_kernel(
    float* __restrict__ yz, float* __restrict__ jp,
    const float* __restrict__ W1, const float* __restrict__ b1,
    const float* __restrict__ b2,
    const float* __restrict__ W3, const float* __restrict__ b3,
    const unsigned short* __restrict__ w2b,
    const unsigned short* __restrict__ w2t,
    float* __restrict__ ws_sum, float* __restrict__ out_lp) {
  extern __shared__ char smraw[];
  unsigned short* sH1b = (unsigned short*)(smraw + OB_H1);
  unsigned short* sGb  = (unsigned short*)(smraw + OB_G);
  float* sW3f = (float*)(smraw + OB_W3F);
  float* sR   = (float*)(smraw + OB_R);
  float* sPRM = (float*)(smraw + OB_PRM);   // 2 x 192 floats
  float* sGZ  = (float*)(smraw + OB_GZ);
  float* sZ1  = (float*)(smraw + OB_Z1);
  float* sLD  = (float*)(smraw + OB_LD);
  float* sZQ  = (float*)(smraw + OB_ZQ);
  float* sRed = (float*)(smraw + OB_RED);

  const int tid  = threadIdx.x;
  const int lane = tid & 63;
  const int w    = __builtin_amdgcn_readfirstlane(tid >> 6);  // 0..3
  const int e    = tid & 15;                     // element (scalar phases)
  const int grp  = tid >> 4;                     // 0..15
  const int lm   = lane & 15, lq = lane >> 4;    // MFMA lane coords
  const int blk  = blockIdx.x;

  // ---- init ----
  float z_a = 0.f, z_b = 0.f;     // z[i], z[6+i] held by tid<96 (i=tid>>4)
  if (tid < 96) {
    int i = tid >> 4;
    z_a = yz[(blk * EPB + e) * 12 + i];
    z_b = yz[(blk * EPB + e) * 12 + 6 + i];
    sZ1[i * EPB + e] = z_b;
  }
  if (tid < 16) { sLD[tid] = 0.f; sZQ[tid] = 0.f; }
  if (tid == 0) sRed[0] = 0.f;
  for (int idx = tid; idx < 576; idx += 256) sGZ[idx] = 0.f;
  for (int idx = tid; idx < 384; idx += 256) sPRM[idx] = 0.f;
  for (int idx = tid; idx < 72 * EPB; idx += 256) {
    int rt = idx >> 4, ee = idx & 15;
    sR[idx] = jp[(blk * EPB + ee) * 72 + rt];
  }
  __syncthreads();

  for (int l = NLAYER - 1; l >= 0; --l) {
    const float* W1l = W1 + l * HID * 6;
    const float* b1l = b1 + l * HID;
    const float* b2l = b2 + l * HID;
    const float* W3l = W3 + l * NDIN * HID;
    const float* b3l = b3 + l * NDIN;
    const unsigned short* w2bl = w2b + l * HID * HID;
    const unsigned short* w2tl = w2t + l * HID * HID;
    float* cur = sPRM + (l & 1) * 192;          // this layer's prm/tf/es
    float* prv = sPRM + ((l + 1) & 1) * 192;    // previous layer's tf/es

    // ==== Phase A (merged): stage W1+W3f, zero cur, V5(l+1), F1(l) ======
    if (tid < 192) {
      const float* wr = W1l + tid * 6;
      unsigned* dst = (unsigned*)(smraw + OB_W1 + tid * 12);
      dst[0] = pk2(wr[0], wr[1]);
      dst[1] = pk2(wr[2], wr[3]);
      dst[2] = pk2(wr[4], wr[5]);
    }
    for (int idx = tid; idx < 2304; idx += 256) {   // W3f [j][t], stride 12
      int t = idx / 192, j = idx - t * 192;
      sW3f[j * W3ST + t] = W3l[idx];
    }
    if (tid < 192) cur[tid] = 0.f;
    if (l != NLAYER - 1) {                          // V5 of layer l+1
      for (int idx = tid; idx < 576; idx += 256) {
        int i = idx / 96, rem = idx - i * 96;
        int r = rem >> 4, e5 = rem & 15;
        float r1  = sR[(r * 12 + i) * EPB + e5];
        float r2o = sR[(r * 12 + 6 + i) * EPB + e5];
        float es  = prv[(2 * i + 1) * EPB + e5];
        sR[(r * 12 + i) * EPB + e5]     = r2o + sGZ[i * 96 + rem];
        sR[(r * 12 + 6 + i) * EPB + e5] = r1 * es;
        sGZ[i * 96 + rem] = 0.f;
      }
    }
    {                                               // F1: 12 rows per grp
      float z1v[6];
      #pragma unroll
      for (int i = 0; i < 6; ++i) z1v[i] = sZ1[i * EPB + e];
      #pragma unroll
      for (int ch = 0; ch < 2; ++ch) {
        int j0 = grp * 12 + ch * 6;
        float hv[6];
        #pragma unroll
        for (int jj = 0; jj < 6; ++jj) {
          int j = j0 + jj;
          float acc = b1l[j];
          #pragma unroll
          for (int i = 0; i < 6; ++i) acc = fmaf(W1l[j * 6 + i], z1v[i], acc);
          hv[jj] = fmaxf(acc, 0.f);
        }
        unsigned* dst = (unsigned*)&sH1b[e * EST + j0];
        dst[0] = pk2(hv[0], hv[1]);
        dst[1] = pk2(hv[2], hv[3]);
        dst[2] = pk2(hv[4], hv[5]);
      }
    }
    __syncthreads();

    // ==== Phase B: S1 = F2 MFMA; wave w: 3 m-tiles (w, w+4, w+8) =======
    {
      f4v acc2[3] = {{0,0,0,0},{0,0,0,0},{0,0,0,0}};
      #pragma unroll 2
      for (int kk = 0; kk < 6; ++kk) {
        int jo = kk * 32 + lq * 8;
        s8v Bv = *(const s8v*)&sH1b[lm * EST + jo];
        #pragma unroll
        for (int s = 0; s < 3; ++s) {
          s8v A = *(const s8v*)(w2bl + ((w + s * 4) * 16 + lm) * HID + jo);
          acc2[s] = MFMA16(A, Bv, acc2[s]);
        }
      }
      #pragma unroll
      for (int s = 0; s < 3; ++s) {
        int jb2 = (w + s * 4) * 16 + lq * 4;
        float hv[4];
        #pragma unroll
        for (int rg = 0; rg < 4; ++rg)
          hv[rg] = fmaxf(acc2[s][rg] + b2l[jb2 + rg], 0.f);
        unsigned* dst = (unsigned*)sGb + ((lm * EST + jb2) >> 1);
        dst[0] = pk2(hv[0], hv[1]);
        dst[1] = pk2(hv[2], hv[3]);
        float pp[12];
        #pragma unroll
        for (int t = 0; t < 12; ++t) pp[t] = 0.f;
        #pragma unroll
        for (int rg = 0; rg < 4; ++rg) {
          const float* w3r = sW3f + (jb2 + rg) * W3ST;
          float v = hv[rg];
          #pragma unroll
          for (int t = 0; t < 12; ++t) pp[t] = fmaf(w3r[t], v, pp[t]);
        }
        #pragma unroll
        for (int t = 0; t < 12; ++t) {
          float v = pp[t];
          v += __shfl_xor(v, 16);
          v += __shfl_xor(v, 32);
          if (lane < 16) atomicAdd(&cur[t * EPB + lane], v);
        }
      }
    }
    __syncthreads();

    // ==== Phase C: U — coupling update; cur becomes tf@2i, es@2i+1 ======
    if (tid < 96) {
      int i = tid >> 4;
      float sh = b3l[2 * i]     + cur[(2 * i) * EPB + e];
      float sr = b3l[2 * i + 1] + cur[(2 * i + 1) * EPB + e];
      float s  = 2.f * tanhf(0.5f * sr);
      float es = expf(s), en = expf(-s);
      float tv = z_a - sh;
      z_a = z_b;
      z_b = tv * en;
      sZ1[i * EPB + e] = z_b;
      cur[(2 * i) * EPB + e]     = tv * (1.f - 0.25f * s * s);  // tf
      cur[(2 * i + 1) * EPB + e] = es;                          // es
      atomicAdd(&sLD[e], -s);
    }
    __syncthreads();

    // ==== Phase D: full-G build — all 6 cotangent rows, one pass =======
    {
      unsigned mbits = 0;
      {
        const unsigned* hp = (const unsigned*)&sGb[e * EST + grp * 12];
        #pragma unroll
        for (int c = 0; c < 6; ++c) {
          unsigned m = hp[c];
          mbits |= ((m & 0xffffu) ? 1u : 0u) << (2 * c);
          mbits |= ((m >> 16)     ? 1u : 0u) << (2 * c + 1);
        }
      }
      float tf[6];
      #pragma unroll
      for (int c = 0; c < 6; ++c) tf[c] = cur[(2 * c) * EPB + e];
      float r1[6][6];
      #pragma unroll
      for (int r = 0; r < 6; ++r)
        #pragma unroll
        for (int c = 0; c < 6; ++c)
          r1[r][c] = sR[(r * 12 + c) * EPB + e];
      #pragma unroll
      for (int ch = 0; ch < 2; ++ch) {
        int j0 = grp * 12 + ch * 6;
        #pragma unroll
        for (int pr = 0; pr < 3; ++pr) {
          const float* wp0 = sW3f + (j0 + 2 * pr)     * W3ST;
          const float* wp1 = sW3f + (j0 + 2 * pr + 1) * W3ST;
          float wc0[6], wc1[6];
          #pragma unroll
          for (int c = 0; c < 6; ++c) {
            wc0[c] = fmaf(tf[c], wp0[2 * c + 1], wp0[2 * c]);
            wc1[c] = fmaf(tf[c], wp1[2 * c + 1], wp1[2 * c]);
          }
          unsigned b0 = (mbits >> (ch * 6 + 2 * pr))     & 1u;
          unsigned b1 = (mbits >> (ch * 6 + 2 * pr + 1)) & 1u;
          #pragma unroll
          for (int r = 0; r < 6; ++r) {
            float a0 = 0.f, a1 = 0.f;
            #pragma unroll
            for (int c = 0; c < 6; ++c) {
              a0 = fmaf(wc0[c], r1[r][c], a0);
              a1 = fmaf(wc1[c], r1[r][c], a1);
            }
            *(unsigned*)&sGb[(r * 16 + e) * EST + j0 + 2 * pr] =
                pk2(b0 ? a0 : 0.f, b1 ? a1 : 0.f);
          }
        }
      }
    }
    __syncthreads();

    // ==== Phase E: V3 full 96 rows, 3m x 6n per wave, 2 chunks =========
    // No barrier between chunks: G is read-only here. n-tile t covers G
    // rows [16t,16t+16): cotangent row r = t, element = lm -> h1 mask is
    // sH1b[lm] for every t (one mask pair per p).
    {
      const int mtg = w * 3;                       // {0,3,6,9}
      #pragma unroll 1
      for (int nc = 0; nc < 2; ++nc) {
        f4v acc[3][3] = {{{0,0,0,0},{0,0,0,0},{0,0,0,0}},
                         {{0,0,0,0},{0,0,0,0},{0,0,0,0}},
                         {{0,0,0,0},{0,0,0,0},{0,0,0,0}}};
        #pragma unroll 2
        for (int kk = 0; kk < 6; ++kk) {
          int jo = kk * 32 + lq * 8;
          s8v A[3], Bv[3];
          #pragma unroll
          for (int p = 0; p < 3; ++p)
            A[p] = *(const s8v*)(w2tl + ((mtg + p) * 16 + lm) * HID + jo);
          #pragma unroll
          for (int q = 0; q < 3; ++q)
            Bv[q] = *(const s8v*)&sGb[((nc * 3 + q) * 16 + lm) * EST + jo];
          #pragma unroll
          for (int p = 0; p < 3; ++p)
            #pragma unroll
            for (int q = 0; q < 3; ++q)
              acc[p][q] = MFMA16(A[p], Bv[q], acc[p][q]);
        }
        float pz[3][6];
        #pragma unroll
        for (int q = 0; q < 3; ++q)
          #pragma unroll
          for (int i = 0; i < 6; ++i) pz[q][i] = 0.f;
        #pragma unroll
        for (int p = 0; p < 3; ++p) {
          int kb = (mtg + p) * 16 + lq * 4;
          const unsigned* mp = (const unsigned*)&sH1b[lm * EST + kb];
          unsigned mm0 = mp[0], mm1 = mp[1];
          #pragma unroll
          for (int rg = 0; rg < 4; ++rg) {   // stream w1v per-rg (12-B rows)
            const unsigned* wp =
                (const unsigned*)(smraw + OB_W1 + (kb + rg) * 12);
            unsigned wx = wp[0], wy = wp[1], wz = wp[2];
            float w0 = blo(wx), w1c = bhi(wx), w2c = blo(wy);
            float w3c = bhi(wy), w4c = blo(wz), w5c = bhi(wz);
            unsigned mm = (rg >> 1) ? mm1 : mm0;
            unsigned short hb = (rg & 1) ? (unsigned short)(mm >> 16)
                                         : (unsigned short)(mm & 0xffffu);
            #pragma unroll
            for (int q = 0; q < 3; ++q) {
              float val = hb ? acc[p][q][rg] : 0.f;
              pz[q][0] = fmaf(w0, val, pz[q][0]);
              pz[q][1] = fmaf(w1c, val, pz[q][1]);
              pz[q][2] = fmaf(w2c, val, pz[q][2]);
              pz[q][3] = fmaf(w3c, val, pz[q][3]);
              pz[q][4] = fmaf(w4c, val, pz[q][4]);
              pz[q][5] = fmaf(w5c, val, pz[q][5]);
            }
          }
        }
        #pragma unroll
        for (int q = 0; q < 3; ++q)
          #pragma unroll
          for (int i = 0; i < 6; ++i) {
            float v = pz[q][i];
            v += __shfl_xor(v, 16);
            v += __shfl_xor(v, 32);
            if (lane < 16)
              atomicAdd(&sGZ[i * 96 + (nc * 3 + q) * 16 + lane], v);
          }
      }
    }
    __syncthreads();
  }

  // ---- final V5 (layer 0, parity 0) + z/lp; then jp writeback ----
  {
    float* prv0 = sPRM;                             // (0 & 1) == 0
    for (int idx = tid; idx < 576; idx += 256) {
      int i = idx / 96, rem = idx - i * 96;
      int r = rem >> 4, e5 = rem & 15;
      float r1  = sR[(r * 12 + i) * EPB + e5];
      float r2o = sR[(r * 12 + 6 + i) * EPB + e5];
      float es  = prv0[(2 * i + 1) * EPB + e5];
      sR[(r * 12 + i) * EPB + e5]     = r2o + sGZ[i * 96 + rem];
      sR[(r * 12 + 6 + i) * EPB + e5] = r1 * es;
    }
  }
  if (tid < 96) {
    int i = tid >> 4;
    yz[(blk * EPB + e) * 12 + i]     = z_a;
    yz[(blk * EPB + e) * 12 + 6 + i] = z_b;
    atomicAdd(&sZQ[e], fmaf(z_a, z_a, z_b * z_b));
  }
  __syncthreads();
  if (tid < 16)
    out_lp[blk * EPB + tid] = sLD[tid] - 11.027262398456072f - 0.5f * sZQ[tid];

  float part = 0.f;
  for (int idx = tid; idx < 72 * EPB; idx += 256) {
    int rt = idx >> 4, ee = idx & 15;
    float v = sR[idx];
    jp[(blk * EPB + ee) * 72 + rt] = v;
    part = fmaf(v, v, part);
  }
  #pragma unroll
  for (int off = 32; off > 0; off >>= 1) part += __shfl_down(part, off, 64);
  if ((tid & 63) == 0) atomicAdd(&sRed[0], part);
  __syncthreads();
  if (tid == 0) atomicAdd(ws_sum, sRed[0]);
}

// ---------------------------------------------------------------------
// kl_kernel R24 (verified): 4 slices/element, grid 256x256, A staged in
// LDS; partials shfl-reduced in the 4-lane group; slice 0 stores.
__global__ __launch_bounds__(256) void kl_kernel(
    const float* __restrict__ zin, const float* __restrict__ jpin,
    const float* __restrict__ Wsym, const float* __restrict__ lvd,
    const float* __restrict__ ws_sum, float* __restrict__ out_kl) {
  __shared__ float sA[NBASE * 144];        // 38,016 B
  const int tid   = threadIdx.x;
  const int elem  = (blockIdx.x * 256 + tid) >> 2;
  const int slice = tid & 3;

  for (int idx = tid; idx < NBASE * 144; idx += 256) {
    int m = idx / 144, r = idx - m * 144;
    int j = r / 12, i = r - j * 12;
    sA[idx] = Wsym[m * 144 + j * 12 + i] - Wsym[m * 144 + i * 12 + j];
  }
  __syncthreads();

  float z[12];
  #pragma unroll
  for (int i = 0; i < 12; ++i) z[i] = zin[elem * 12 + i];
  float scale = 1.0f / sqrtf(ws_sum[0]);
  float Jp[6][12];
  #pragma unroll
  for (int n = 0; n < 6; ++n)
    #pragma unroll
    for (int j = 0; j < 12; ++j)
      Jp[n][j] = jpin[elem * 72 + n * 12 + j] * scale;

  float Sq[78];
  #pragma unroll
  for (int i = 0; i < 78; ++i) Sq[i] = 0.f;
  float tq = 0.f, tpq = 0.f;

  const int m0 = (slice < 2) ? slice * 17 : 34 + (slice - 2) * 16;
  const int m1 = m0 + ((slice < 2) ? 17 : 16);
  for (int m = m0; m < m1; ++m) {
    const float* Am = sA + m * 144;
    float jq[12];
    #pragma unroll
    for (int j = 0; j < 12; ++j) {
      float acc = 0.f;
      #pragma unroll
      for (int i = 0; i < 12; ++i)
        acc = fmaf(Am[j * 12 + i], z[i], acc);
      jq[j] = acc;
    }
    #pragma unroll
    for (int i = 0; i < 12; ++i) {
      tq = fmaf(jq[i], jq[i], tq);
      #pragma unroll
      for (int j = 0; j <= i; ++j)
        Sq[i * (i + 1) / 2 + j] = fmaf(jq[i], jq[j], Sq[i * (i + 1) / 2 + j]);
    }
    #pragma unroll
    for (int n = 0; n < 6; ++n) {
      float d = 0.f;
      #pragma unroll
      for (int j = 0; j < 12; ++j) d = fmaf(Jp[n][j], jq[j], d);
      tpq = fmaf(d, d, tpq);
    }
  }

  #pragma unroll
  for (int i = 0; i < 78; ++i) {
    float v = Sq[i];
    v += __shfl_xor(v, 1);
    v += __shfl_xor(v, 2);
    Sq[i] = v;
  }
  tq  += __shfl_xor(tq, 1);  tq  += __shfl_xor(tq, 2);
  tpq += __shfl_xor(tpq, 1); tpq += __shfl_xor(tpq, 2);

  float Dv[12], Db[12];
  #pragma unroll
  for (int j = 0; j < 12; ++j) Dv[j] = expf(-lvd[j]);

  float mh = 0.f;
  #pragma unroll
  for (int i = 0; i < 12; ++i) mh += Sq[i * (i + 1) / 2 + i] + Dv[i];
  float norm_H = fmaxf(mh * (1.f / 12.f), 1e-6f);
  #pragma unroll
  for (int i = 0; i < 12; ++i) Sq[i * (i + 1) / 2 + i] += Dv[i] + 1e-3f * norm_H;
  float sumDb = 0.f;
  #pragma unroll
  for (int j = 0; j < 12; ++j) { Db[j] = Dv[j] + 1e-3f * norm_H; sumDb += Db[j]; }

  float M[21];
  #pragma unroll
  for (int n = 0; n < 6; ++n)
    #pragma unroll
    for (int mm = 0; mm <= n; ++mm) {
      float acc = 0.f;
      #pragma unroll
      for (int j = 0; j < 12; ++j) acc = fmaf(Jp[n][j], Jp[mm][j], acc);
      M[n * (n + 1) / 2 + mm] = acc;
    }
  float md = 0.f;
  #pragma unroll
  for (int i = 0; i < 6; ++i) md += M[i * (i + 1) / 2 + i];
  float norm_M = fmaxf(md * (1.f / 6.f) + EPSP, 1e-6f);
  #pragma unroll
  for (int i = 0; i < 6; ++i) M[i * (i + 1) / 2 + i] += EPSP + 1e-3f * norm_M;

  float trace_p = 0.f;
  #pragma unroll
  for (int n = 0; n < 6; ++n)
    #pragma unroll
    for (int j = 0; j < 12; ++j)
      trace_p = fmaf(Jp[n][j] * Jp[n][j], Db[j], trace_p);

  float trace = (EPSP + 1e-3f * norm_M) * (sumDb + tq) + trace_p + tpq;

  float ldM = 0.f;
  #pragma unroll
  for (int jc = 0; jc < 6; ++jc) {
    float d = M[jc * (jc + 1) / 2 + jc];
    #pragma unroll
    for (int k = 0; k < jc; ++k) d -= M[jc * (jc + 1) / 2 + k] * M[jc * (jc + 1) / 2 + k];
    d = sqrtf(d);
    ldM += logf(d);
    float di = 1.f / d;
    M[jc * (jc + 1) / 2 + jc] = d;
    #pragma unroll
    for (int i2 = jc + 1; i2 < 6; ++i2) {
      float v = M[i2 * (i2 + 1) / 2 + jc];
      #pragma unroll
      for (int k = 0; k < jc; ++k) v -= M[i2 * (i2 + 1) / 2 + k] * M[jc * (jc + 1) / 2 + k];
      M[i2 * (i2 + 1) / 2 + jc] = v * di;
    }
  }

  float ldH = 0.f;
  #pragma unroll
  for (int jc = 0; jc < 12; ++jc) {
    float d = Sq[jc * (jc + 1) / 2 + jc];
    #pragma unroll
    for (int k = 0; k < jc; ++k) d -= Sq[jc * (jc + 1) / 2 + k] * Sq[jc * (jc + 1) / 2 + k];
    d = sqrtf(d);
    ldH += logf(d);
    float di = 1.f / d;
    Sq[jc * (jc + 1) / 2 + jc] = d;
    #pragma unroll
    for (int i2 = jc + 1; i2 < 12; ++i2) {
      float v = Sq[i2 * (i2 + 1) / 2 + jc];
      #pragma unroll
      for (int k = 0; k < jc; ++k) v -= Sq[i2 * (i2 + 1) / 2 + k] * Sq[jc * (jc + 1) / 2 + k];
      Sq[i2 * (i2 + 1) / 2 + jc] = v * di;
    }
  }

  float logdet_p = 2.f * ldM + 6.f * logf(EPSP);
  float logdet_q = 2.f * ldH;
  if (slice == 0)
    out_kl[elem] = 0.5f * (trace - (logdet_p + logdet_q) - 12.f);
}

// ---------------------------------------------------------------------
extern "C" void kernel_launch(void* const* d_in, const int* in_sizes, int n_in,
                              void* d_out, int out_size, void* d_ws, size_t ws_size,
                              hipStream_t stream) {
  (void)in_sizes; (void)n_in; (void)out_size; (void)ws_size;
  float* y    = (float*)d_in[0];   // consumed, then overwritten with z
  float* Jp   = (float*)d_in[1];   // consumed, then overwritten with pullback Jp
  const float* W1   = (const float*)d_in[2];
  const float* b1   = (const float*)d_in[3];
  const float* W2   = (const float*)d_in[4];
  const float* b2   = (const float*)d_in[5];
  const float* W3   = (const float*)d_in[6];
  const float* b3   = (const float*)d_in[7];
  const float* Wsym = (const float*)d_in[8];
  const float* lvd  = (const float*)d_in[9];
  float* out = (float*)d_out;      // fp32: [log_prob (B), kl (B)]

  float* ws_sum = (float*)d_ws;
  unsigned short* w2b = (unsigned short*)((char*)d_ws + 256);
  unsigned short* w2t = (unsigned short*)((char*)d_ws + 256 +
                                          NLAYER * HID * HID * 2);
  hipMemsetAsync(d_ws, 0, 4, stream);

  hipFuncSetAttribute((const void*)flow_kernel,
                      hipFuncAttributeMaxDynamicSharedMemorySize, SMEM_BYTES);

  prep_kernel<<<3456, 256, 0, stream>>>(W2, w2b, w2t);
  flow_kernel<<<BTOT / EPB, 256, SMEM_BYTES, stream>>>(
      y, Jp, W1, b1, b2, W3, b3, w2b, w2t, ws_sum, out);
  kl_kernel<<<BTOT * 4 / 256, 256, 0, stream>>>(y, Jp, Wsym, lvd, ws_sum,
                                                out + BTOT);
}